// Round 1
// 237.697 us; speedup vs baseline: 1.2286x; 1.2286x over previous
//
#include <hip/hip_runtime.h>
#include <math.h>

#define D_MODEL 768
#define D_STATE 16
#define D_CONV  4
#define D_INNER 1536
#define BATCH   2
#define SEQ     512
#define M_ROWS  (BATCH * SEQ)            // 1024
#define N_XZ    (2 * D_INNER)            // 3072
#define N_XDBL  (D_INNER + 2 * D_STATE)  // 1568

typedef _Float16 half8 __attribute__((ext_vector_type(8)));
typedef float  f32x4  __attribute__((ext_vector_type(4)));
typedef unsigned short ushort_t;
typedef ushort_t ushort8_t __attribute__((ext_vector_type(8)));

// ---- fp16 helpers (RNE via HW cvt), raw ushort storage ----
__device__ __forceinline__ ushort_t f2h(float f) {
    _Float16 h = (_Float16)f;
    return *(ushort_t*)&h;
}
// pack 8 consecutive fp32 -> 8 fp16 (16 B) at d
__device__ __forceinline__ void pack8(const float* s, ushort_t* d) {
    ushort8_t o;
#pragma unroll
    for (int j = 0; j < 8; ++j) o[j] = f2h(s[j]);
    *(ushort8_t*)d = o;
}
// async global(16B/lane) -> LDS (wave-uniform base + lane*16)  [m03/m97/m104]
__device__ __forceinline__ void gld16(const ushort_t* g, void* l) {
    __builtin_amdgcn_global_load_lds((const __attribute__((address_space(1))) void*)g,
                                     (__attribute__((address_space(3))) void*)l, 16, 0, 0);
}

// ---------------------------------------------------------------------------
// Fused pack: x -> xs, W_in -> w1, W_x -> w2 (plain fp16, h-only).
// ---------------------------------------------------------------------------
#define SX  (M_ROWS * D_MODEL)
#define SW1 (N_XZ * D_MODEL)
#define SW2 (N_XDBL * D_INNER)
__global__ __launch_bounds__(256) void split3_kernel(
    const float* __restrict__ x, const float* __restrict__ win,
    const float* __restrict__ wx,
    ushort_t* __restrict__ xs, ushort_t* __restrict__ w1, ushort_t* __restrict__ w2)
{
    long i = ((long)blockIdx.x * 256 + threadIdx.x) * 8;
    const float* src; ushort_t* dst; long base;
    if (i < SX)            { src = x;   dst = xs; base = i; }
    else if (i < SX + SW1) { src = win; dst = w1; base = i - SX; }
    else                   { src = wx;  dst = w2; base = i - SX - SW1; }
    float v[8];
    *(float4*)(v)     = *(const float4*)(src + base);
    *(float4*)(v + 4) = *(const float4*)(src + base + 4);
    pack8(v, dst + base);
}

// ---------------------------------------------------------------------------
// Dual pack: W_dt -> w1, W_out -> wout (both regions dead by then).
// ---------------------------------------------------------------------------
#define SWDT (D_INNER * D_INNER)
#define SWO  (D_MODEL * D_INNER)
__global__ __launch_bounds__(256) void split2_kernel(
    const float* __restrict__ wdt, const float* __restrict__ wo,
    ushort_t* __restrict__ w1, ushort_t* __restrict__ wout)
{
    long i = ((long)blockIdx.x * 256 + threadIdx.x) * 8;
    const float* src; ushort_t* dst; long base;
    if (i < SWDT) { src = wdt; dst = w1;   base = i; }
    else          { src = wo;  dst = wout; base = i - SWDT; }
    float v[8];
    *(float4*)(v)     = *(const float4*)(src + base);
    *(float4*)(v + 4) = *(const float4*)(src + base + 4);
    pack8(v, dst + base);
}

// ---------------------------------------------------------------------------
// Single-MFMA fp16 GEMM — m97 structure: 256 threads, 128x128 tile, 4 waves
// of 64x64, double-buffered 32 KB LDS staged via global_load_lds width=16.
// A,B plain fp16 row-major [rows][K]. XCD-compact swizzle; partial z slices.
// Precision: operand quantization 2^-11 RNE; output contribution ~5e-6,
// below the ~3e-5 scan-path rounding floor (see session journal).
// ---------------------------------------------------------------------------
__global__ __launch_bounds__(256) void gemm_lds(
    const ushort_t* __restrict__ A, int lda,   // lda = K in elems
    const ushort_t* __restrict__ B, int ldb,
    float* __restrict__ Cbase, long pstride, int ldc,
    int N, int kc)
{
    __shared__ ushort_t smA[2][4096];          // [buf][128 rows x 32 k] = 16 KB
    __shared__ ushort_t smB[2][4096];          // 16 KB

    const int tid  = threadIdx.x;
    const int w    = tid >> 6;
    const int lane = tid & 63;
    const int lr   = lane & 15;
    const int lq   = lane >> 4;

    const int Gx = gridDim.x, Gy = gridDim.y;
    const int T = Gx * Gy * gridDim.z;
    const int f = blockIdx.x + Gx * (blockIdx.y + Gy * blockIdx.z);
    const int g = (T & 7) ? f : ((f & 7) * (T >> 3) + (f >> 3));
    const int bx = g % Gx;
    const int by = (g / Gx) % Gy;
    const int z  = g / (Gx * Gy);
    float* __restrict__ C = Cbase + (long)z * pstride;

    const int bm = by * 128;
    const int bn = bx * 128;
    const int k0base = z * kc;

    // LDS layout per matrix: [group g=row/16][koct lq][row lr][8 halves]
    // -> linear dest base g*512, lane (lq*16+lr) writes its 16 B. Fragment
    // read = 16-lane groups at 16 B stride -> conflict-free (2/bank).
    auto stage = [&](int buf, int k0) {
#pragma unroll
        for (int i = 0; i < 2; ++i) {
            const int gA = i * 4 + w;                    // wave-uniform 0..7
            const int rA = bm + gA * 16 + lr;
            gld16(A + (long)rA * lda + k0 + lq * 8, &smA[buf][gA * 512]);
        }
#pragma unroll
        for (int i = 0; i < 2; ++i) {
            const int gB = i * 4 + w;
            int rB = bn + gB * 16 + lr; if (rB >= N) rB = N - 1;
            gld16(B + (long)rB * ldb + k0 + lq * 8, &smB[buf][gB * 512]);
        }
    };

    f32x4 acc[4][4] = {};
    const int wm = (w & 1) * 64;
    const int wn = (w >> 1) * 64;

    stage(0, k0base);
    __syncthreads();
    const int nIter = kc >> 5;
    for (int it = 0; it < nIter; ++it) {
        const int buf = it & 1;
        if (it + 1 < nIter) stage(buf ^ 1, k0base + (it + 1) * 32);

        half8 ah[4], bh[4];
#pragma unroll
        for (int mt = 0; mt < 4; ++mt)
            ah[mt] = *(const half8*)&smA[buf][(((w & 1) * 4 + mt) * 512) + lq * 128 + lr * 8];
#pragma unroll
        for (int nt = 0; nt < 4; ++nt)
            bh[nt] = *(const half8*)&smB[buf][(((w >> 1) * 4 + nt) * 512) + lq * 128 + lr * 8];
#pragma unroll
        for (int mt = 0; mt < 4; ++mt)
#pragma unroll
            for (int nt = 0; nt < 4; ++nt)
                acc[mt][nt] = __builtin_amdgcn_mfma_f32_16x16x32_f16(ah[mt], bh[nt], acc[mt][nt], 0, 0, 0);
        __syncthreads();   // drains next-buf staging; frees cur buf
    }

    // C/D layout: col = lane&15, row = (lane>>4)*4 + reg  [m89/m91, dtype-indep]
#pragma unroll
    for (int mt = 0; mt < 4; ++mt)
#pragma unroll
        for (int nt = 0; nt < 4; ++nt)
#pragma unroll
            for (int r = 0; r < 4; ++r) {
                int row = bm + wm + mt * 16 + lq * 4 + r;
                int col = bn + wn + nt * 16 + lr;
                if (col >= N) continue;
                C[(long)row * ldc + col] = acc[mt][nt][r];
            }
}

// ---------------------------------------------------------------------------
// Depthwise causal conv + bias + SiLU, fused with GEMM1 split-K merge.
// ---------------------------------------------------------------------------
__global__ __launch_bounds__(256) void conv_silu_kernel(
    const float* __restrict__ p0, const float* __restrict__ p1,
    const float* __restrict__ conv_w,
    const float* __restrict__ conv_b,
    float* __restrict__ xconvT,
    float* __restrict__ zsiluT,
    ushort_t* __restrict__ xc)
{
    int idx = blockIdx.x * blockDim.x + threadIdx.x;
    if (idx >= M_ROWS * D_INNER) return;
    int d = idx % D_INNER;
    int r = idx / D_INNER;
    int l = r % SEQ;
    float acc = conv_b[d];
#pragma unroll
    for (int k = 0; k < D_CONV; ++k) {
        if (l - (D_CONV - 1) + k >= 0) {
            long o = (long)(r - (D_CONV - 1 - k)) * N_XZ + d;
            acc = fmaf(conv_w[d * D_CONV + k], p0[o] + p1[o], acc);
        }
    }
    float s = acc / (1.f + expf(-acc));
    xconvT[(long)d * M_ROWS + r] = s;
    xc[(long)r * D_INNER + d] = f2h(s);
    long oz = (long)r * N_XZ + D_INNER + d;
    float zv = p0[oz] + p1[oz];
    zsiluT[(long)d * M_ROWS + r] = zv / (1.f + expf(-zv));
}

// ---------------------------------------------------------------------------
// GEMM3 epilogue: f = sum of 3 partials (stride ps) -> xd fp16 [1024][1568];
// cols >= 1536 also stored transposed fp32 into BCT.
// ---------------------------------------------------------------------------
__global__ __launch_bounds__(256) void ep_xdbl_kernel(
    const float* __restrict__ P, long ps,
    ushort_t* __restrict__ xd, float* __restrict__ BCT)
{
    long i = ((long)blockIdx.x * 256 + threadIdx.x) * 8;
    if (i >= (long)M_ROWS * N_XDBL) return;
    int row = (int)(i / N_XDBL);
    int col = (int)(i - (long)row * N_XDBL);    // multiple of 8
    float f[8];
#pragma unroll
    for (int j = 0; j < 8; ++j) f[j] = P[i + j] + P[i + j + ps] + P[i + j + 2 * ps];
    pack8(f, xd + i);
    if (col >= D_INNER) {
#pragma unroll
        for (int j = 0; j < 8; ++j)
            BCT[(long)(col + j - D_INNER) * M_ROWS + row] = f[j];
    }
}

// ---------------------------------------------------------------------------
// GEMM6 epilogue: out = sum of 6 partials (stride ps).
// ---------------------------------------------------------------------------
__global__ __launch_bounds__(256) void ep_merge_kernel(
    const float* __restrict__ P, long ps, float* __restrict__ out)
{
    long i = ((long)blockIdx.x * 256 + threadIdx.x) * 8;
    if (i >= (long)M_ROWS * D_MODEL) return;
    float o[8];
#pragma unroll
    for (int j = 0; j < 8; ++j) {
        float v = 0.f;
#pragma unroll
        for (int z = 0; z < 6; ++z) v += P[i + j + z * ps];
        o[j] = v;
    }
    *(float4*)(out + i)     = *(float4*)(o);
    *(float4*)(out + i + 4) = *(float4*)(o + 4);
}

// ---------------------------------------------------------------------------
// Wave-per-(b,d) register scan, fused with the GEMM4 softplus merge.
// ---------------------------------------------------------------------------
__global__ __launch_bounds__(256) void scan_kernel(
    const float* __restrict__ P, long ps,       // GEMM4 partials (1536,1024) x4
    const float* __restrict__ b_dt,
    const float* __restrict__ xconvT,
    const float* __restrict__ zsiluT,
    const float* __restrict__ BCT,              // (32, 1024)
    const float* __restrict__ A_log,
    const float* __restrict__ Dp,
    float* __restrict__ uT)
{
    const int bid = blockIdx.x;
    const int b   = bid / (D_INNER / 4);
    const int dg  = bid % (D_INNER / 4);
    const int tid = threadIdx.x;
    const int w   = tid >> 6;
    const int t   = tid & 63;
    const int d   = dg * 4 + w;
    const int base = b * SEQ;
    const int l0 = 8 * t;

    const long od = (long)d * M_ROWS + base + l0;
    const float bdt = b_dt[d];
    float dl[8], xr[8], yac[8];
#pragma unroll
    for (int i = 0; i < 8; ++i) {
        float v = P[od + i] + P[od + i + ps] + P[od + i + 2 * ps] + P[od + i + 3 * ps] + bdt;
        dl[i] = fmaxf(v, 0.f) + log1pf(expf(-fabsf(v)));   // softplus (fused)
        xr[i] = xconvT[od + i];
        yac[i] = 0.f;
    }

    for (int n = 0; n < D_STATE; ++n) {
        const float Adn = -expf(A_log[d * D_STATE + n]);
        const float4* Bp = (const float4*)(BCT + (long)n * M_ROWS + base + l0);
        float4 b0 = Bp[0], b1 = Bp[1];
        float Bv[8] = {b0.x, b0.y, b0.z, b0.w, b1.x, b1.y, b1.z, b1.w};
        float c[8], v[8];
#pragma unroll
        for (int i = 0; i < 8; ++i) {
            c[i] = expf(dl[i] * Adn) + 1e-12f;
            v[i] = fabsf(dl[i] * Bv[i] * xr[i]) + 1e-12f;
        }
#pragma unroll
        for (int p = 0; p < 8; p += 2) { v[p+1] = fmaf(c[p+1], v[p+1], v[p]); c[p+1] *= c[p]; }
        v[3] = fmaf(c[3], v[3], v[1]); c[3] *= c[1];
        v[7] = fmaf(c[7], v[7], v[5]); c[7] *= c[5];
        v[7] = fmaf(c[7], v[7], v[3]); c[7] *= c[3];
        float c7 = c[7], v7 = v[7];
#pragma unroll
        for (int h = 1; h <= 32; h <<= 1) {
            float vl = __shfl_up(v7, (unsigned)h);
            float cl = __shfl_up(c7, (unsigned)h);
            bool right = ((t & (2 * h - 1)) == (2 * h - 1));
            if (right) { v7 = fmaf(c7, v7, vl); c7 *= cl; }
        }
#pragma unroll
        for (int h = 32; h >= 1; h >>= 1) {
            float vl = __shfl_up(v7, (unsigned)h);
            float vr = __shfl_down(v7, (unsigned)h);
            bool right = ((t & (2 * h - 1)) == (2 * h - 1));
            bool left  = ((t & (2 * h - 1)) == (h - 1));
            float nv = v7;
            if (right) nv = fmaf(c7, v7, vl);
            if (left)  nv = vr;
            v7 = nv;
        }
        v[7] = v7;
        c[7] = c7;
        float tmp;
        tmp = v[7]; v[7] = fmaf(c[7], v[7], v[3]); v[3] = tmp;
        tmp = v[3]; v[3] = fmaf(c[3], v[3], v[1]); v[1] = tmp;
        tmp = v[7]; v[7] = fmaf(c[7], v[7], v[5]); v[5] = tmp;
#pragma unroll
        for (int p = 0; p < 8; p += 2) {
            tmp = v[p+1]; v[p+1] = fmaf(c[p+1], v[p+1], v[p]); v[p] = tmp;
        }
        const float4* Cp = (const float4*)(BCT + (long)(16 + n) * M_ROWS + base + l0);
        float4 c0 = Cp[0], c1 = Cp[1];
        float Cv[8] = {c0.x, c0.y, c0.z, c0.w, c1.x, c1.y, c1.z, c1.w};
#pragma unroll
        for (int i = 0; i < 8; ++i) yac[i] = fmaf(v[i], Cv[i], yac[i]);
    }

    const float Dpd = Dp[d];
#pragma unroll
    for (int i = 0; i < 8; ++i) {
        float uv = fmaf(xr[i], Dpd, yac[i]) * zsiluT[od + i];
        uT[od + i] = uv;
    }
}

// ---------------------------------------------------------------------------
// Transpose + pack: uT (1536,1024) fp32 -> u fp16 (1024,1536).
// ---------------------------------------------------------------------------
__global__ __launch_bounds__(256) void transpose_split_kernel(
    const float* __restrict__ uT, ushort_t* __restrict__ u)
{
    __shared__ float T[64][65];
    const int m0 = blockIdx.x * 64;
    const int d0 = blockIdx.y * 64;
    const int c  = threadIdx.x & 63;
    const int rr = threadIdx.x >> 6;
#pragma unroll
    for (int p = 0; p < 64; p += 4)
        T[p + rr][c] = uT[(long)(d0 + p + rr) * M_ROWS + m0 + c];
    __syncthreads();
#pragma unroll
    for (int p = 0; p < 64; p += 4) {
        int rm = p + rr;
        float v = T[c][rm];
        u[(long)(m0 + rm) * D_INNER + (d0 + c)] = f2h(v);
    }
}

// ---------------------------------------------------------------------------
extern "C" void kernel_launch(void* const* d_in, const int* in_sizes, int n_in,
                              void* d_out, int out_size, void* d_ws, size_t ws_size,
                              hipStream_t stream)
{
    (void)in_sizes; (void)n_in; (void)out_size; (void)ws_size;

    const float* x      = (const float*)d_in[0];
    const float* W_in   = (const float*)d_in[1];
    const float* conv_w = (const float*)d_in[2];
    const float* conv_b = (const float*)d_in[3];
    const float* W_x    = (const float*)d_in[4];
    const float* W_dt   = (const float*)d_in[5];
    const float* b_dt   = (const float*)d_in[6];
    const float* A_log  = (const float*)d_in[7];
    const float* Dp     = (const float*)d_in[8];
    const float* W_out  = (const float*)d_in[9];
    float* out = (float*)d_out;

    // workspace ~60.9 MB (was 69.7). Liveness:
    //  P (25.2 MB): G1 p0/p1 -> G3 p0..p2 -> G4 p0..p3 (scan reads, fused
    //    softplus) -> dead after scan -> G6 p0..p5.
    //  w1buf: W_in fp16 (G1 B) -> W_dt fp16 (G4 A).
    //  w2buf: W_x fp16 (G3 B) -> W_out fp16 (G6 B).
    //  xcu:   xc fp16 (G3 A) -> u fp16 (G6 A).
    //  xd dead after G4; uT has its own region (fp16 shrink freed the space).
    float* ws = (float*)d_ws;
    long off = 0;
    float* P      = ws + off; off += 2L * M_ROWS * N_XZ;          // 6,291,456 fl
    float* xconvT = ws + off; off += (long)D_INNER * M_ROWS;
    float* zsiluT = ws + off; off += (long)D_INNER * M_ROWS;
    float* uT     = ws + off; off += (long)D_INNER * M_ROWS;
    float* xcu    = ws + off; off += (long)M_ROWS * D_INNER / 2;  // fp16 region
    float* xsbuf  = ws + off; off += (long)M_ROWS * D_MODEL / 2;
    float* w1buf  = ws + off; off += (long)N_XZ * D_MODEL / 2;
    float* w2buf  = ws + off; off += (long)N_XDBL * D_INNER / 2;
    float* xdbuf  = ws + off; off += (long)M_ROWS * N_XDBL / 2;
    float* BCT    = ws + off; off += (long)2 * D_STATE * M_ROWS;

    ushort_t* xs   = (ushort_t*)xsbuf;          // x fp16 (G1 A)
    ushort_t* w1   = (ushort_t*)w1buf;          // W_in fp16 -> W_dt fp16
    ushort_t* w2   = (ushort_t*)w2buf;          // W_x fp16 -> W_out fp16
    ushort_t* xc   = (ushort_t*)xcu;            // conv fp16 out (G3 A)
    ushort_t* xd   = (ushort_t*)xdbuf;          // x_dbl fp16 (G4 B)
    ushort_t* u_i  = (ushort_t*)xcu;            // u fp16 (G6 A; xc dead)
    float* P6      = P;                         // G6 partials (P dead post-scan)

    const long psG4 = (long)D_INNER * M_ROWS;

    dim3 blk(256);

    // 1) pack x, W_in, W_x -> fp16
    hipLaunchKernelGGL(split3_kernel, dim3((SX + SW1 + SW2) / 2048), blk, 0, stream,
                       x, W_in, W_x, xs, w1, w2);
    // 2) xz = x @ W_in^T  (M=1024,N=3072,K=768), z=2 -> P[0],P[1]
    hipLaunchKernelGGL(gemm_lds, dim3(N_XZ / 128, M_ROWS / 128, 2), blk, 0, stream,
                       xs, D_MODEL, w1, D_MODEL,
                       P, (long)M_ROWS * N_XZ, N_XZ, N_XZ, D_MODEL / 2);
    // 3) conv + silu (fuses GEMM1 partial merge)
    hipLaunchKernelGGL(conv_silu_kernel, dim3((M_ROWS * D_INNER) / 256), blk, 0, stream,
                       P, P + (long)M_ROWS * N_XZ, conv_w, conv_b, xconvT, zsiluT, xc);
    // 4) xconv @ W_x^T  (M=1024,N=1568,K=1536), z=3 -> P partials
    hipLaunchKernelGGL(gemm_lds, dim3((N_XDBL + 127) / 128, M_ROWS / 128, 3), blk, 0, stream,
                       xc, D_INNER, w2, D_INNER,
                       P, (long)M_ROWS * N_XDBL, N_XDBL, N_XDBL, D_INNER / 3);
    // 5) merge partials -> xd fp16 + BCT
    hipLaunchKernelGGL(ep_xdbl_kernel, dim3((M_ROWS * N_XDBL) / 2048), blk, 0, stream,
                       P, (long)M_ROWS * N_XDBL, xd, BCT);
    // 6) dual pack: W_dt -> w1, W_out -> w2 (both regions now dead)
    hipLaunchKernelGGL(split2_kernel, dim3((SWDT + SWO) / 2048), blk, 0, stream,
                       W_dt, W_out, w1, w2);
    // 7) W_dt @ x_dbl^T  (M=1536,N=1024,K=1536), z=4 -> P partials
    hipLaunchKernelGGL(gemm_lds, dim3(M_ROWS / 128, D_INNER / 128, 4), blk, 0, stream,
                       w1, D_INNER, xd, N_XDBL,
                       P, psG4, M_ROWS, M_ROWS, D_INNER / 4);
    // 8) scan (fused softplus merge of the 4 partials) -> uT
    hipLaunchKernelGGL(scan_kernel, dim3(BATCH * (D_INNER / 4)), blk, 0, stream,
                       P, psG4, b_dt, xconvT, zsiluT, BCT, A_log, Dp, uT);
    // 9) transpose+pack uT -> u fp16 (xcu; xc dead after G3)
    hipLaunchKernelGGL(transpose_split_kernel, dim3(M_ROWS / 64, D_INNER / 64), blk, 0, stream,
                       uT, u_i);
    // 10) u @ W_out^T  (M=1024,N=768,K=1536), z=6 -> P6
    hipLaunchKernelGGL(gemm_lds, dim3(D_MODEL / 128, M_ROWS / 128, 6), blk, 0, stream,
                       u_i, D_INNER, w2, D_INNER,
                       P6, (long)M_ROWS * D_MODEL, D_MODEL, D_MODEL, D_INNER / 6);
    // 11) merge -> out
    hipLaunchKernelGGL(ep_merge_kernel, dim3((M_ROWS * D_MODEL) / 2048), blk, 0, stream,
                       P6, (long)M_ROWS * D_MODEL, out);
}

// Round 2
// 223.146 us; speedup vs baseline: 1.3087x; 1.0652x over previous
//
#include <hip/hip_runtime.h>
#include <math.h>

#define D_MODEL 768
#define D_STATE 16
#define D_CONV  4
#define D_INNER 1536
#define BATCH   2
#define SEQ     512
#define M_ROWS  (BATCH * SEQ)            // 1024
#define N_XZ    (2 * D_INNER)            // 3072
#define N_XDBL  (D_INNER + 2 * D_STATE)  // 1568

typedef _Float16 half8 __attribute__((ext_vector_type(8)));
typedef float  f32x4  __attribute__((ext_vector_type(4)));
typedef unsigned short ushort_t;
typedef ushort_t ushort8_t __attribute__((ext_vector_type(8)));

// ---- fp16 helpers (RNE via HW cvt), raw ushort storage ----
__device__ __forceinline__ ushort_t f2h(float f) {
    _Float16 h = (_Float16)f;
    return *(ushort_t*)&h;
}
// pack 8 consecutive fp32 -> 8 fp16 (16 B) at d
__device__ __forceinline__ void pack8(const float* s, ushort_t* d) {
    ushort8_t o;
#pragma unroll
    for (int j = 0; j < 8; ++j) o[j] = f2h(s[j]);
    *(ushort8_t*)d = o;
}
// async global(16B/lane) -> LDS (wave-uniform base + lane*16)  [m03/m97/m104]
__device__ __forceinline__ void gld16(const ushort_t* g, void* l) {
    __builtin_amdgcn_global_load_lds((const __attribute__((address_space(1))) void*)g,
                                     (__attribute__((address_space(3))) void*)l, 16, 0, 0);
}

// ---------------------------------------------------------------------------
// Fused pack: x -> xs, W_in -> w1, W_x -> w2 (plain fp16, h-only).
// ---------------------------------------------------------------------------
#define SX  (M_ROWS * D_MODEL)
#define SW1 (N_XZ * D_MODEL)
#define SW2 (N_XDBL * D_INNER)
__global__ __launch_bounds__(256) void split3_kernel(
    const float* __restrict__ x, const float* __restrict__ win,
    const float* __restrict__ wx,
    ushort_t* __restrict__ xs, ushort_t* __restrict__ w1, ushort_t* __restrict__ w2)
{
    long i = ((long)blockIdx.x * 256 + threadIdx.x) * 8;
    const float* src; ushort_t* dst; long base;
    if (i < SX)            { src = x;   dst = xs; base = i; }
    else if (i < SX + SW1) { src = win; dst = w1; base = i - SX; }
    else                   { src = wx;  dst = w2; base = i - SX - SW1; }
    float v[8];
    *(float4*)(v)     = *(const float4*)(src + base);
    *(float4*)(v + 4) = *(const float4*)(src + base + 4);
    pack8(v, dst + base);
}

// ---------------------------------------------------------------------------
// Dual pack: W_dt -> w1, W_out -> wout (both regions dead by then).
// ---------------------------------------------------------------------------
#define SWDT (D_INNER * D_INNER)
#define SWO  (D_MODEL * D_INNER)
__global__ __launch_bounds__(256) void split2_kernel(
    const float* __restrict__ wdt, const float* __restrict__ wo,
    ushort_t* __restrict__ w1, ushort_t* __restrict__ wout)
{
    long i = ((long)blockIdx.x * 256 + threadIdx.x) * 8;
    const float* src; ushort_t* dst; long base;
    if (i < SWDT) { src = wdt; dst = w1;   base = i; }
    else          { src = wo;  dst = wout; base = i - SWDT; }
    float v[8];
    *(float4*)(v)     = *(const float4*)(src + base);
    *(float4*)(v + 4) = *(const float4*)(src + base + 4);
    pack8(v, dst + base);
}

// ---------------------------------------------------------------------------
// Single-MFMA fp16 GEMM — m97 structure: 256 threads, 128x128 tile, 4 waves
// of 64x64, double-buffered 32 KB LDS staged via global_load_lds width=16.
// A,B plain fp16 row-major [rows][K]. XCD-compact swizzle; partial z slices.
// ---------------------------------------------------------------------------
__global__ __launch_bounds__(256) void gemm_lds(
    const ushort_t* __restrict__ A, int lda,   // lda = K in elems
    const ushort_t* __restrict__ B, int ldb,
    float* __restrict__ Cbase, long pstride, int ldc,
    int N, int kc)
{
    __shared__ ushort_t smA[2][4096];          // [buf][128 rows x 32 k] = 16 KB
    __shared__ ushort_t smB[2][4096];          // 16 KB

    const int tid  = threadIdx.x;
    const int w    = tid >> 6;
    const int lane = tid & 63;
    const int lr   = lane & 15;
    const int lq   = lane >> 4;

    const int Gx = gridDim.x, Gy = gridDim.y;
    const int T = Gx * Gy * gridDim.z;
    const int f = blockIdx.x + Gx * (blockIdx.y + Gy * blockIdx.z);
    const int g = (T & 7) ? f : ((f & 7) * (T >> 3) + (f >> 3));
    const int bx = g % Gx;
    const int by = (g / Gx) % Gy;
    const int z  = g / (Gx * Gy);
    float* __restrict__ C = Cbase + (long)z * pstride;

    const int bm = by * 128;
    const int bn = bx * 128;
    const int k0base = z * kc;

    auto stage = [&](int buf, int k0) {
#pragma unroll
        for (int i = 0; i < 2; ++i) {
            const int gA = i * 4 + w;                    // wave-uniform 0..7
            const int rA = bm + gA * 16 + lr;
            gld16(A + (long)rA * lda + k0 + lq * 8, &smA[buf][gA * 512]);
        }
#pragma unroll
        for (int i = 0; i < 2; ++i) {
            const int gB = i * 4 + w;
            int rB = bn + gB * 16 + lr; if (rB >= N) rB = N - 1;
            gld16(B + (long)rB * ldb + k0 + lq * 8, &smB[buf][gB * 512]);
        }
    };

    f32x4 acc[4][4] = {};
    const int wm = (w & 1) * 64;
    const int wn = (w >> 1) * 64;

    stage(0, k0base);
    __syncthreads();
    const int nIter = kc >> 5;
    for (int it = 0; it < nIter; ++it) {
        const int buf = it & 1;
        if (it + 1 < nIter) stage(buf ^ 1, k0base + (it + 1) * 32);

        half8 ah[4], bh[4];
#pragma unroll
        for (int mt = 0; mt < 4; ++mt)
            ah[mt] = *(const half8*)&smA[buf][(((w & 1) * 4 + mt) * 512) + lq * 128 + lr * 8];
#pragma unroll
        for (int nt = 0; nt < 4; ++nt)
            bh[nt] = *(const half8*)&smB[buf][(((w >> 1) * 4 + nt) * 512) + lq * 128 + lr * 8];
#pragma unroll
        for (int mt = 0; mt < 4; ++mt)
#pragma unroll
            for (int nt = 0; nt < 4; ++nt)
                acc[mt][nt] = __builtin_amdgcn_mfma_f32_16x16x32_f16(ah[mt], bh[nt], acc[mt][nt], 0, 0, 0);
        __syncthreads();   // drains next-buf staging; frees cur buf
    }

    // C/D layout: col = lane&15, row = (lane>>4)*4 + reg  [m89/m91, dtype-indep]
#pragma unroll
    for (int mt = 0; mt < 4; ++mt)
#pragma unroll
        for (int nt = 0; nt < 4; ++nt)
#pragma unroll
            for (int r = 0; r < 4; ++r) {
                int row = bm + wm + mt * 16 + lq * 4 + r;
                int col = bn + wn + nt * 16 + lr;
                if (col >= N) continue;
                C[(long)row * ldc + col] = acc[mt][nt][r];
            }
}

// ---------------------------------------------------------------------------
// Depthwise causal conv + bias + SiLU, fused with GEMM1 split-K merge.
// ---------------------------------------------------------------------------
__global__ __launch_bounds__(256) void conv_silu_kernel(
    const float* __restrict__ p0, const float* __restrict__ p1,
    const float* __restrict__ conv_w,
    const float* __restrict__ conv_b,
    float* __restrict__ xconvT,
    float* __restrict__ zsiluT,
    ushort_t* __restrict__ xc)
{
    int idx = blockIdx.x * blockDim.x + threadIdx.x;
    if (idx >= M_ROWS * D_INNER) return;
    int d = idx % D_INNER;
    int r = idx / D_INNER;
    int l = r % SEQ;
    float acc = conv_b[d];
#pragma unroll
    for (int k = 0; k < D_CONV; ++k) {
        if (l - (D_CONV - 1) + k >= 0) {
            long o = (long)(r - (D_CONV - 1 - k)) * N_XZ + d;
            acc = fmaf(conv_w[d * D_CONV + k], p0[o] + p1[o], acc);
        }
    }
    float s = acc / (1.f + expf(-acc));
    xconvT[(long)d * M_ROWS + r] = s;
    xc[(long)r * D_INNER + d] = f2h(s);
    long oz = (long)r * N_XZ + D_INNER + d;
    float zv = p0[oz] + p1[oz];
    zsiluT[(long)d * M_ROWS + r] = zv / (1.f + expf(-zv));
}

// ---------------------------------------------------------------------------
// GEMM3 epilogue: f = sum of 3 partials (stride ps) -> xd fp16 [1024][1568];
// cols >= 1536 also stored transposed fp32 into BCT.
// ---------------------------------------------------------------------------
__global__ __launch_bounds__(256) void ep_xdbl_kernel(
    const float* __restrict__ P, long ps,
    ushort_t* __restrict__ xd, float* __restrict__ BCT)
{
    long i = ((long)blockIdx.x * 256 + threadIdx.x) * 8;
    if (i >= (long)M_ROWS * N_XDBL) return;
    int row = (int)(i / N_XDBL);
    int col = (int)(i - (long)row * N_XDBL);    // multiple of 8
    float f[8];
#pragma unroll
    for (int j = 0; j < 8; ++j) f[j] = P[i + j] + P[i + j + ps] + P[i + j + 2 * ps];
    pack8(f, xd + i);
    if (col >= D_INNER) {
#pragma unroll
        for (int j = 0; j < 8; ++j)
            BCT[(long)(col + j - D_INNER) * M_ROWS + row] = f[j];
    }
}

// ---------------------------------------------------------------------------
// GEMM6 epilogue: out = sum of 6 partials (stride ps).
// ---------------------------------------------------------------------------
__global__ __launch_bounds__(256) void ep_merge_kernel(
    const float* __restrict__ P, long ps, float* __restrict__ out)
{
    long i = ((long)blockIdx.x * 256 + threadIdx.x) * 8;
    if (i >= (long)M_ROWS * D_MODEL) return;
    float o[8];
#pragma unroll
    for (int j = 0; j < 8; ++j) {
        float v = 0.f;
#pragma unroll
        for (int z = 0; z < 6; ++z) v += P[i + j + z * ps];
        o[j] = v;
    }
    *(float4*)(out + i)     = *(float4*)(o);
    *(float4*)(out + i + 4) = *(float4*)(o + 4);
}

// ---------------------------------------------------------------------------
// Scan v2 — one block per (b,d), 4 waves split the 16 states (4 each).
// Phase 1: cooperative softplus-merge of the 4 GEMM4 partials -> dl,xr in LDS
//          (transposed [j][t] layout => conflict-free per-lane reads).
// Phase 2: per wave, 4 states: c=__expf(dl*A), v=|dl*xr*B|; 7-op compose tree
//          -> 6-stage Kogge-Stone inclusive lane scan -> exclusive carry via
//          shfl_up(1) -> 8 serial FMAs distribute; yac += s*C.
// Phase 3: LDS reduce of yac across waves (transposed, conflict-free);
//          wave 0 applies D-term + z-gate and writes uT.
// ---------------------------------------------------------------------------
__global__ __launch_bounds__(256) void scan_kernel(
    const float* __restrict__ P, long ps,       // GEMM4 partials (1536,1024) x4
    const float* __restrict__ b_dt,
    const float* __restrict__ xconvT,
    const float* __restrict__ zsiluT,
    const float* __restrict__ BCT,              // (32, 1024)
    const float* __restrict__ A_log,
    const float* __restrict__ Dp,
    float* __restrict__ uT)
{
    __shared__ float dlT[512];
    __shared__ float xrT[512];
    __shared__ float red[3 * 512];

    const int bid = blockIdx.x;
    const int b   = bid / D_INNER;
    const int d   = bid % D_INNER;
    const int tid = threadIdx.x;
    const int w   = tid >> 6;
    const int t   = tid & 63;
    const long od = (long)d * M_ROWS + b * SEQ;

    const float bdt = b_dt[d];
#pragma unroll
    for (int q = 0; q < 2; ++q) {
        const int l = tid + q * 256;
        float v = P[od + l] + P[od + l + ps] + P[od + l + 2 * ps] + P[od + l + 3 * ps] + bdt;
        float sp = fmaxf(v, 0.f) + log1pf(expf(-fabsf(v)));   // softplus (fused merge)
        const int li = (l & 7) * 64 + (l >> 3);               // transposed
        dlT[li] = sp;
        xrT[li] = xconvT[od + l];
    }
    __syncthreads();

    float dl[8], xr[8], dx[8], yac[8];
#pragma unroll
    for (int j = 0; j < 8; ++j) {
        dl[j] = dlT[j * 64 + t];
        xr[j] = xrT[j * 64 + t];
        dx[j] = dl[j] * xr[j];
        yac[j] = 0.f;
    }
    const int l0 = 8 * t;

#pragma unroll
    for (int nn = 0; nn < 4; ++nn) {
        const int n = w * 4 + nn;
        const float Adn = -expf(A_log[d * D_STATE + n]);
        const float4* Bp = (const float4*)(BCT + (long)n * M_ROWS + b * SEQ + l0);
        float4 b0 = Bp[0], b1 = Bp[1];
        float Bv[8] = {b0.x, b0.y, b0.z, b0.w, b1.x, b1.y, b1.z, b1.w};
        float c[8], v[8];
#pragma unroll
        for (int j = 0; j < 8; ++j) {
            c[j] = __expf(dl[j] * Adn);
            v[j] = fabsf(dx[j] * Bv[j]);
        }
        // compose tree: (cR*cL, cR*vL + vR), 7 composes, depth 3
        float c01 = c[1] * c[0], v01 = fmaf(c[1], v[0], v[1]);
        float c23 = c[3] * c[2], v23 = fmaf(c[3], v[2], v[3]);
        float c45 = c[5] * c[4], v45 = fmaf(c[5], v[4], v[5]);
        float c67 = c[7] * c[6], v67 = fmaf(c[7], v[6], v[7]);
        float c03 = c23 * c01,  v03 = fmaf(c23, v01, v23);
        float c47 = c67 * c45,  v47 = fmaf(c67, v45, v67);
        float cA  = c47 * c03,  vA  = fmaf(c47, v03, v47);
        // Kogge-Stone inclusive scan over 64 lanes (6 stages)
#pragma unroll
        for (int h = 1; h <= 32; h <<= 1) {
            float cl = __shfl_up(cA, (unsigned)h);
            float vl = __shfl_up(vA, (unsigned)h);
            if (t >= h) { vA = fmaf(cA, vl, vA); cA = cA * cl; }
        }
        // exclusive carry: state entering this lane = inclusive V of lane t-1
        float s = __shfl_up(vA, 1u);
        if (t == 0) s = 0.f;
        const float4* Cp = (const float4*)(BCT + (long)(16 + n) * M_ROWS + b * SEQ + l0);
        float4 c0 = Cp[0], c1 = Cp[1];
        float Cv[8] = {c0.x, c0.y, c0.z, c0.w, c1.x, c1.y, c1.z, c1.w};
#pragma unroll
        for (int j = 0; j < 8; ++j) {
            s = fmaf(c[j], s, v[j]);
            yac[j] = fmaf(s, Cv[j], yac[j]);
        }
    }

    // cross-wave reduce (transposed layout => conflict-free)
    if (w) {
#pragma unroll
        for (int j = 0; j < 8; ++j) red[(w - 1) * 512 + j * 64 + t] = yac[j];
    }
    __syncthreads();
    if (w == 0) {
        const float Dpd = Dp[d];
#pragma unroll
        for (int j = 0; j < 8; ++j) {
            float y = yac[j] + red[j * 64 + t] + red[512 + j * 64 + t] + red[1024 + j * 64 + t];
            float uv = fmaf(xr[j], Dpd, y) * zsiluT[od + l0 + j];
            uT[od + l0 + j] = uv;
        }
    }
}

// ---------------------------------------------------------------------------
// Transpose + pack: uT (1536,1024) fp32 -> u fp16 (1024,1536).
// ---------------------------------------------------------------------------
__global__ __launch_bounds__(256) void transpose_split_kernel(
    const float* __restrict__ uT, ushort_t* __restrict__ u)
{
    __shared__ float T[64][65];
    const int m0 = blockIdx.x * 64;
    const int d0 = blockIdx.y * 64;
    const int c  = threadIdx.x & 63;
    const int rr = threadIdx.x >> 6;
#pragma unroll
    for (int p = 0; p < 64; p += 4)
        T[p + rr][c] = uT[(long)(d0 + p + rr) * M_ROWS + m0 + c];
    __syncthreads();
#pragma unroll
    for (int p = 0; p < 64; p += 4) {
        int rm = p + rr;
        float v = T[c][rm];
        u[(long)(m0 + rm) * D_INNER + (d0 + c)] = f2h(v);
    }
}

// ---------------------------------------------------------------------------
extern "C" void kernel_launch(void* const* d_in, const int* in_sizes, int n_in,
                              void* d_out, int out_size, void* d_ws, size_t ws_size,
                              hipStream_t stream)
{
    (void)in_sizes; (void)n_in; (void)out_size; (void)ws_size;

    const float* x      = (const float*)d_in[0];
    const float* W_in   = (const float*)d_in[1];
    const float* conv_w = (const float*)d_in[2];
    const float* conv_b = (const float*)d_in[3];
    const float* W_x    = (const float*)d_in[4];
    const float* W_dt   = (const float*)d_in[5];
    const float* b_dt   = (const float*)d_in[6];
    const float* A_log  = (const float*)d_in[7];
    const float* Dp     = (const float*)d_in[8];
    const float* W_out  = (const float*)d_in[9];
    float* out = (float*)d_out;

    float* ws = (float*)d_ws;
    long off = 0;
    float* P      = ws + off; off += 2L * M_ROWS * N_XZ;          // 6,291,456 fl
    float* xconvT = ws + off; off += (long)D_INNER * M_ROWS;
    float* zsiluT = ws + off; off += (long)D_INNER * M_ROWS;
    float* uT     = ws + off; off += (long)D_INNER * M_ROWS;
    float* xcu    = ws + off; off += (long)M_ROWS * D_INNER / 2;  // fp16 region
    float* xsbuf  = ws + off; off += (long)M_ROWS * D_MODEL / 2;
    float* w1buf  = ws + off; off += (long)N_XZ * D_MODEL / 2;
    float* w2buf  = ws + off; off += (long)N_XDBL * D_INNER / 2;
    float* xdbuf  = ws + off; off += (long)M_ROWS * N_XDBL / 2;
    float* BCT    = ws + off; off += (long)2 * D_STATE * M_ROWS;

    ushort_t* xs   = (ushort_t*)xsbuf;          // x fp16 (G1 A)
    ushort_t* w1   = (ushort_t*)w1buf;          // W_in fp16 -> W_dt fp16
    ushort_t* w2   = (ushort_t*)w2buf;          // W_x fp16 -> W_out fp16
    ushort_t* xc   = (ushort_t*)xcu;            // conv fp16 out (G3 A)
    ushort_t* xd   = (ushort_t*)xdbuf;          // x_dbl fp16 (G4 B)
    ushort_t* u_i  = (ushort_t*)xcu;            // u fp16 (G6 A; xc dead)
    float* P6      = P;                         // G6 partials (P dead post-scan)

    const long psG4 = (long)D_INNER * M_ROWS;

    dim3 blk(256);

    // 1) pack x, W_in, W_x -> fp16
    hipLaunchKernelGGL(split3_kernel, dim3((SX + SW1 + SW2) / 2048), blk, 0, stream,
                       x, W_in, W_x, xs, w1, w2);
    // 2) xz = x @ W_in^T  (M=1024,N=3072,K=768), z=2 -> P[0],P[1]
    hipLaunchKernelGGL(gemm_lds, dim3(N_XZ / 128, M_ROWS / 128, 2), blk, 0, stream,
                       xs, D_MODEL, w1, D_MODEL,
                       P, (long)M_ROWS * N_XZ, N_XZ, N_XZ, D_MODEL / 2);
    // 3) conv + silu (fuses GEMM1 partial merge)
    hipLaunchKernelGGL(conv_silu_kernel, dim3((M_ROWS * D_INNER) / 256), blk, 0, stream,
                       P, P + (long)M_ROWS * N_XZ, conv_w, conv_b, xconvT, zsiluT, xc);
    // 4) xconv @ W_x^T  (M=1024,N=1568,K=1536), z=3 -> P partials
    hipLaunchKernelGGL(gemm_lds, dim3((N_XDBL + 127) / 128, M_ROWS / 128, 3), blk, 0, stream,
                       xc, D_INNER, w2, D_INNER,
                       P, (long)M_ROWS * N_XDBL, N_XDBL, N_XDBL, D_INNER / 3);
    // 5) merge partials -> xd fp16 + BCT
    hipLaunchKernelGGL(ep_xdbl_kernel, dim3((M_ROWS * N_XDBL) / 2048), blk, 0, stream,
                       P, (long)M_ROWS * N_XDBL, xd, BCT);
    // 6) dual pack: W_dt -> w1, W_out -> w2 (both regions now dead)
    hipLaunchKernelGGL(split2_kernel, dim3((SWDT + SWO) / 2048), blk, 0, stream,
                       W_dt, W_out, w1, w2);
    // 7) W_dt @ x_dbl^T  (M=1536,N=1024,K=1536), z=4 -> P partials
    hipLaunchKernelGGL(gemm_lds, dim3(M_ROWS / 128, D_INNER / 128, 4), blk, 0, stream,
                       w1, D_INNER, xd, N_XDBL,
                       P, psG4, M_ROWS, M_ROWS, D_INNER / 4);
    // 8) scan v2: one block per (b,d), 4-wave n-split -> uT
    hipLaunchKernelGGL(scan_kernel, dim3(BATCH * D_INNER), blk, 0, stream,
                       P, psG4, b_dt, xconvT, zsiluT, BCT, A_log, Dp, uT);
    // 9) transpose+pack uT -> u fp16 (xcu; xc dead after G3)
    hipLaunchKernelGGL(transpose_split_kernel, dim3(M_ROWS / 64, D_INNER / 64), blk, 0, stream,
                       uT, u_i);
    // 10) u @ W_out^T  (M=1024,N=768,K=1536), z=6 -> P6
    hipLaunchKernelGGL(gemm_lds, dim3(D_MODEL / 128, M_ROWS / 128, 6), blk, 0, stream,
                       u_i, D_INNER, w2, D_INNER,
                       P6, (long)M_ROWS * D_MODEL, D_MODEL, D_MODEL, D_INNER / 6);
    // 11) merge -> out
    hipLaunchKernelGGL(ep_merge_kernel, dim3((M_ROWS * D_MODEL) / 2048), blk, 0, stream,
                       P6, (long)M_ROWS * D_MODEL, out);
}